// Round 1
// baseline (396.620 us; speedup 1.0000x reference)
//
#include <hip/hip_runtime.h>
#include <hip/hip_bf16.h>

// I2I CrossAttention + gate fusion, MI355X (gfx950).
// B=1, C=128, D*H*W = N = 8192, HEADS=4, DH=32.
// Pipeline (all bf16 MFMA 16x16x32, LDS-free fragment loads from L2-resident ws):
//   wprep: weights fp32 -> bf16 (Wq pre-scaled by SCALE*log2e)
//   transpose: feat1/feat2 [c][n] fp32 -> [n][c] bf16
//   gemmT: QT/KT [n][128], V [c][n], AOT, G1T (relu), GATE (sigmoid, fp32)
//   attn: flash-style, S^T = K*Q (lane-fixed n), exact softmax with max=0
//         (logits bounded ~0.5 by construction), PV via shared k-bijection
//   combine: out = gate*feat1 + (1-gate)*attn_out

typedef __attribute__((ext_vector_type(4))) float f32x4;
typedef __attribute__((ext_vector_type(8))) short s16x8;
typedef __attribute__((ext_vector_type(4))) short s16x4;

#define MFMA_BF16(A,B,C) __builtin_amdgcn_mfma_f32_16x16x32_bf16((A),(B),(C),0,0,0)

static __device__ inline short bf16s(float f){
  __hip_bfloat16 h = __float2bfloat16(f);
  return __builtin_bit_cast(short, h);
}

// ---------------- weight prep: fp32 -> bf16 (Wq scaled) ----------------
__global__ __launch_bounds__(256) void wprep(
    const float* __restrict__ Wq, const float* __restrict__ Wk,
    const float* __restrict__ Wv, const float* __restrict__ Wo,
    const float* __restrict__ Wg1, const float* __restrict__ Wg2,
    __hip_bfloat16* __restrict__ out)
{
  int i = blockIdx.x*256 + threadIdx.x;              // 0..114687
  const float SCQ = 0.17677669529663689f * 1.44269504088896340f; // (1/sqrt(32))*log2(e)
  float v;
  if      (i < 16384) v = Wq[i]*SCQ;
  else if (i < 32768) v = Wk[i-16384];
  else if (i < 49152) v = Wv[i-32768];
  else if (i < 65536) v = Wo[i-49152];
  else if (i < 98304) v = Wg1[i-65536];
  else                v = Wg2[i-98304];
  out[i] = __float2bfloat16(v);
}

// ------------- transpose [128][8192] fp32 -> [8192][128] bf16 -------------
__global__ __launch_bounds__(256) void transpose_to_bf16(
    const float* __restrict__ in, __hip_bfloat16* __restrict__ out)
{
  __shared__ __hip_bfloat16 tile[64][128];   // XOR-swizzled columns
  int tid = threadIdx.x;
  int n0 = blockIdx.x*64;
  int cq = tid>>4;            // 0..15
  int nq = (tid&15)*4;        // 0..60
  #pragma unroll
  for (int r=0;r<8;r++){
    int c = r*16 + cq;
    f32x4 val = *(const f32x4*)&in[c*8192 + n0 + nq];
    #pragma unroll
    for (int i=0;i<4;i++){
      int n = nq + i;
      tile[n][c ^ ((n&7)<<4)] = __float2bfloat16(val[i]);
    }
  }
  __syncthreads();
  int row = tid>>2;           // 0..63
  int cb  = (tid&3)*32;
  #pragma unroll
  for (int k=0;k<4;k++){
    int c0 = cb + 8*k;
    s16x8 v = *(const s16x8*)&tile[row][c0 ^ ((row&7)<<4)];
    *(s16x8*)&out[(n0+row)*128 + c0] = v;
  }
}

// ---------------- generic transposed-output channel-mix GEMM ----------------
// out^T[n][o] = sum_c A[n][c] * Bw[o][c] (+bias). A rows stride 128 bf16.
// ep: 0 = bf16 [n][128] (+bias*bscale)   (QT/KT/AOT)
//     1 = V variant: swapped mfma, bf16 [o][8192]
//     2 = relu -> bf16 [n][128]          (G1T)
//     3 = sigmoid -> fp32 [n][128]       (GATE)
template<int KCH, int SPLIT>
__global__ __launch_bounds__(256) void gemmT(
    const __hip_bfloat16* __restrict__ A1, const __hip_bfloat16* __restrict__ A2,
    const __hip_bfloat16* __restrict__ Bw, const int bstride,
    const float* __restrict__ bias, const float bscale,
    __hip_bfloat16* __restrict__ outb, float* __restrict__ outf, const int ep)
{
  int tid = threadIdx.x;
  int w = tid>>6, lane = tid&63, g = lane>>4, ln = lane&15;
  int n0 = blockIdx.x*16, o0 = w*32;
  f32x4 acc0 = {0.f,0.f,0.f,0.f}, acc1 = {0.f,0.f,0.f,0.f};
  #pragma unroll
  for (int ck=0; ck<KCH; ck++){
    const __hip_bfloat16* As = (ck < SPLIT) ? A1 : A2;
    int cb = ((ck < SPLIT) ? ck : (ck-SPLIT))*32;
    s16x8 af  = *(const s16x8*)&As[(n0+ln)*128 + cb + 8*g];
    s16x8 bf0 = *(const s16x8*)&Bw[(o0+ln)*bstride + ck*32 + 8*g];
    s16x8 bf1 = *(const s16x8*)&Bw[(o0+16+ln)*bstride + ck*32 + 8*g];
    if (ep == 1){
      acc0 = MFMA_BF16(bf0, af, acc0);
      acc1 = MFMA_BF16(bf1, af, acc1);
    } else {
      acc0 = MFMA_BF16(af, bf0, acc0);
      acc1 = MFMA_BF16(af, bf1, acc1);
    }
  }
  if (ep == 1){
    #pragma unroll
    for (int to=0; to<2; to++){
      f32x4 a = to ? acc1 : acc0;
      #pragma unroll
      for (int r=0;r<4;r++){
        int o = o0 + 16*to + 4*g + r;
        int n = n0 + ln;
        outb[o*8192 + n] = __float2bfloat16(a[r] + bias[o]);
      }
    }
  } else {
    float b0 = bias[o0+ln]*bscale, b1 = bias[o0+16+ln]*bscale;
    #pragma unroll
    for (int to=0; to<2; to++){
      f32x4 a = to ? acc1 : acc0;
      float bb = to ? b1 : b0;
      int o = o0 + 16*to + ln;
      #pragma unroll
      for (int r=0;r<4;r++){
        int n = n0 + 4*g + r;
        float v = a[r] + bb;
        if (ep == 2) v = fmaxf(v, 0.f);
        if (ep == 3) outf[n*128 + o] = 1.f/(1.f + exp2f(-1.44269504f*v));
        else         outb[n*128 + o] = __float2bfloat16(v);
      }
    }
  }
}

// ---------------- fused attention (per wave: 16 q-rows, full m sweep) ----------------
__global__ __launch_bounds__(256) void attn(
    const __hip_bfloat16* __restrict__ QT, const __hip_bfloat16* __restrict__ KT,
    const __hip_bfloat16* __restrict__ Vb, __hip_bfloat16* __restrict__ OT)
{
  int tid = threadIdx.x;
  int w = tid>>6, lane = tid&63, g = lane>>4, ln = lane&15;
  int h = blockIdx.y;
  int n = blockIdx.x*64 + w*16 + ln;      // this lane's query column
  s16x8 qf = *(const s16x8*)&QT[n*128 + h*32 + 8*g];   // Q pre-scaled by SCALE*log2e
  const __hip_bfloat16* Kh = KT + h*32;
  const __hip_bfloat16* Vh = Vb + h*32*8192;
  f32x4 acc0 = {0.f,0.f,0.f,0.f}, acc1 = {0.f,0.f,0.f,0.f};
  float psum = 0.f;
  for (int mb=0; mb<8192; mb+=64){
    // S^T tiles: lane holds S^T[m=mb+16r+4g+reg][n]
    f32x4 s[4];
    #pragma unroll
    for (int r=0;r<4;r++){
      s16x8 kf = *(const s16x8*)&Kh[(mb+16*r+ln)*128 + 8*g];
      f32x4 z = {0.f,0.f,0.f,0.f};
      s[r] = MFMA_BF16(kf, qf, z);
    }
    // exact softmax numerator, fixed max=0 (|logit| <= ~0.5 by construction)
    s16x8 pb[2];
    #pragma unroll
    for (int kk=0; kk<2; kk++){
      #pragma unroll
      for (int j=0;j<4;j++){
        float p0 = exp2f(s[2*kk][j]);
        float p1 = exp2f(s[2*kk+1][j]);
        psum += p0 + p1;
        pb[kk][j]   = bf16s(p0);   // m = 32kk + 4g + j
        pb[kk][j+4] = bf16s(p1);   // m = 32kk + 16 + 4g + j
      }
    }
    // PV: O[c][n] += V[c][m] * P^T[m][n]; V loaded with the SAME k-bijection as pb
    #pragma unroll
    for (int kk=0; kk<2; kk++){
      #pragma unroll
      for (int t=0;t<2;t++){
        const __hip_bfloat16* vp = &Vh[(16*t+ln)*8192 + mb + 32*kk + 4*g];
        s16x4 lo = *(const s16x4*)vp;
        s16x4 hi = *(const s16x4*)(vp + 16);
        s16x8 vf = __builtin_shufflevector(lo, hi, 0,1,2,3,4,5,6,7);
        if (t==0) acc0 = MFMA_BF16(vf, pb[kk], acc0);
        else      acc1 = MFMA_BF16(vf, pb[kk], acc1);
      }
    }
  }
  // lane's psum covers its g-quarter of m; reduce across the 4 group-lanes of column n
  psum += __shfl_xor(psum, 16, 64);
  psum += __shfl_xor(psum, 32, 64);
  float inv = 1.f/psum;
  #pragma unroll
  for (int t=0;t<2;t++){
    f32x4 a = t ? acc1 : acc0;
    #pragma unroll
    for (int r=0;r<4;r++)
      OT[n*128 + h*32 + 16*t + 4*g + r] = __float2bfloat16(a[r]*inv);
  }
}

// ---------------- final gated combine ----------------
__global__ __launch_bounds__(256) void combine(
    const float* __restrict__ feat1, const float* __restrict__ gate,
    const __hip_bfloat16* __restrict__ aot, float* __restrict__ out)
{
  int idx = (blockIdx.x*256 + threadIdx.x)*4;
  int c = idx>>13, nn = idx&8191;
  f32x4 f = *(const f32x4*)&feat1[idx];
  f32x4 r;
  #pragma unroll
  for (int i=0;i<4;i++){
    float gt = gate[(nn+i)*128 + c];
    float ao = __bfloat162float(aot[(nn+i)*128 + c]);
    r[i] = gt*f[i] + (1.f-gt)*ao;
  }
  *(f32x4*)&out[idx] = r;
}

extern "C" void kernel_launch(void* const* d_in, const int* in_sizes, int n_in,
                              void* d_out, int out_size, void* d_ws, size_t ws_size,
                              hipStream_t stream)
{
  const float* feat1 = (const float*)d_in[0];
  const float* feat2 = (const float*)d_in[1];
  const float* Wq = (const float*)d_in[2];  const float* bq = (const float*)d_in[3];
  const float* Wk = (const float*)d_in[4];  const float* bk = (const float*)d_in[5];
  const float* Wv = (const float*)d_in[6];  const float* bv = (const float*)d_in[7];
  const float* Wo = (const float*)d_in[8];  const float* bo = (const float*)d_in[9];
  const float* Wg1 = (const float*)d_in[10]; const float* bg1 = (const float*)d_in[11];
  const float* Wg2 = (const float*)d_in[12]; const float* bg2 = (const float*)d_in[13];

  // workspace layout (bf16 elements unless noted); ~20.2 MB total
  __hip_bfloat16* WQb  = (__hip_bfloat16*)d_ws;     // 16384
  __hip_bfloat16* WKb  = WQb + 16384;
  __hip_bfloat16* WVb  = WQb + 32768;
  __hip_bfloat16* WOb  = WQb + 49152;
  __hip_bfloat16* WG1b = WQb + 65536;               // 32768
  __hip_bfloat16* WG2b = WQb + 98304;
  __hip_bfloat16* F1T  = WQb + 114688;              // [8192][128] each below
  __hip_bfloat16* F2T  = F1T + 1048576;
  __hip_bfloat16* QT   = F1T + 2*1048576;
  __hip_bfloat16* KT   = F1T + 3*1048576;
  __hip_bfloat16* Vbf  = F1T + 4*1048576;           // [128][8192]
  __hip_bfloat16* OT   = F1T + 5*1048576;
  __hip_bfloat16* AOT  = F1T + 6*1048576;
  __hip_bfloat16* G1T  = F1T + 7*1048576;
  float*          GATE = (float*)(F1T + 8*1048576); // fp32 [8192][128]

  const float SCQ = 0.17677669529663689f * 1.44269504088896340f;

  wprep<<<448,256,0,stream>>>(Wq,Wk,Wv,Wo,Wg1,Wg2,WQb);
  transpose_to_bf16<<<128,256,0,stream>>>(feat1, F1T);
  transpose_to_bf16<<<128,256,0,stream>>>(feat2, F2T);
  gemmT<4,4><<<512,256,0,stream>>>(F1T,F1T,WQb,128,bq,SCQ, QT ,nullptr,0);
  gemmT<4,4><<<512,256,0,stream>>>(F2T,F2T,WKb,128,bk,1.f, KT ,nullptr,0);
  gemmT<4,4><<<512,256,0,stream>>>(F2T,F2T,WVb,128,bv,1.f, Vbf,nullptr,1);
  attn<<<dim3(128,4),256,0,stream>>>(QT,KT,Vbf,OT);
  gemmT<4,4><<<512,256,0,stream>>>(OT ,OT ,WOb ,128,bo ,1.f, AOT,nullptr,0);
  gemmT<8,4><<<512,256,0,stream>>>(AOT,F1T,WG1b,256,bg1,1.f, G1T,nullptr,2);
  gemmT<4,4><<<512,256,0,stream>>>(G1T,G1T,WG2b,128,bg2,1.f, nullptr,GATE,3);
  combine<<<1024,256,0,stream>>>(feat1, GATE, AOT, (float*)d_out);
}

// Round 2
// 156.921 us; speedup vs baseline: 2.5275x; 2.5275x over previous
//
#include <hip/hip_runtime.h>
#include <hip/hip_bf16.h>

// I2I CrossAttention + gate fusion, MI355X (gfx950).
// B=1, C=128, D*H*W = N = 8192, HEADS=4, DH=32.
// Round 2: attn rebuilt as LDS-staged double-buffered flash kernel.
//   8 waves/block = 4 n-tiles(32 n) x 2 m-halves (in-block split-K via LDS combine)
//   global_load_lds staging with source-side XOR swizzles (linear LDS writes)
//   K reads: ds_read_b128 at 8-phase floor; V reads: ds_read_b64 at 4-phase floor

typedef __attribute__((ext_vector_type(4))) float f32x4;
typedef __attribute__((ext_vector_type(8))) short s16x8;
typedef __attribute__((ext_vector_type(4))) short s16x4;

#define MFMA_BF16(A,B,C) __builtin_amdgcn_mfma_f32_16x16x32_bf16((A),(B),(C),0,0,0)

static __device__ inline short bf16s(float f){
  __hip_bfloat16 h = __float2bfloat16(f);
  return __builtin_bit_cast(short, h);
}

__device__ __forceinline__ void gll16(const void* g, void* l){
  __builtin_amdgcn_global_load_lds(
      (const __attribute__((address_space(1))) void*)g,
      (__attribute__((address_space(3))) void*)l, 16, 0, 0);
}

// ---------------- weight prep: fp32 -> bf16 (Wq scaled) ----------------
__global__ __launch_bounds__(256) void wprep(
    const float* __restrict__ Wq, const float* __restrict__ Wk,
    const float* __restrict__ Wv, const float* __restrict__ Wo,
    const float* __restrict__ Wg1, const float* __restrict__ Wg2,
    __hip_bfloat16* __restrict__ out)
{
  int i = blockIdx.x*256 + threadIdx.x;              // 0..114687
  const float SCQ = 0.17677669529663689f * 1.44269504088896340f;
  float v;
  if      (i < 16384) v = Wq[i]*SCQ;
  else if (i < 32768) v = Wk[i-16384];
  else if (i < 49152) v = Wv[i-32768];
  else if (i < 65536) v = Wo[i-49152];
  else if (i < 98304) v = Wg1[i-65536];
  else                v = Wg2[i-98304];
  out[i] = __float2bfloat16(v);
}

// ------------- transpose [128][8192] fp32 -> [8192][128] bf16 -------------
__global__ __launch_bounds__(256) void transpose_to_bf16(
    const float* __restrict__ in, __hip_bfloat16* __restrict__ out)
{
  __shared__ __hip_bfloat16 tile[64][128];
  int tid = threadIdx.x;
  int n0 = blockIdx.x*64;
  int cq = tid>>4;
  int nq = (tid&15)*4;
  #pragma unroll
  for (int r=0;r<8;r++){
    int c = r*16 + cq;
    f32x4 val = *(const f32x4*)&in[c*8192 + n0 + nq];
    #pragma unroll
    for (int i=0;i<4;i++){
      int n = nq + i;
      tile[n][c ^ ((n&7)<<4)] = __float2bfloat16(val[i]);
    }
  }
  __syncthreads();
  int row = tid>>2;
  int cb  = (tid&3)*32;
  #pragma unroll
  for (int k=0;k<4;k++){
    int c0 = cb + 8*k;
    s16x8 v = *(const s16x8*)&tile[row][c0 ^ ((row&7)<<4)];
    *(s16x8*)&out[(n0+row)*128 + c0] = v;
  }
}

// ---------------- generic transposed-output channel-mix GEMM ----------------
template<int KCH, int SPLIT>
__global__ __launch_bounds__(256) void gemmT(
    const __hip_bfloat16* __restrict__ A1, const __hip_bfloat16* __restrict__ A2,
    const __hip_bfloat16* __restrict__ Bw, const int bstride,
    const float* __restrict__ bias, const float bscale,
    __hip_bfloat16* __restrict__ outb, float* __restrict__ outf, const int ep)
{
  int tid = threadIdx.x;
  int w = tid>>6, lane = tid&63, g = lane>>4, ln = lane&15;
  int n0 = blockIdx.x*16, o0 = w*32;
  f32x4 acc0 = {0.f,0.f,0.f,0.f}, acc1 = {0.f,0.f,0.f,0.f};
  #pragma unroll
  for (int ck=0; ck<KCH; ck++){
    const __hip_bfloat16* As = (ck < SPLIT) ? A1 : A2;
    int cb = ((ck < SPLIT) ? ck : (ck-SPLIT))*32;
    s16x8 af  = *(const s16x8*)&As[(n0+ln)*128 + cb + 8*g];
    s16x8 bf0 = *(const s16x8*)&Bw[(o0+ln)*bstride + ck*32 + 8*g];
    s16x8 bf1 = *(const s16x8*)&Bw[(o0+16+ln)*bstride + ck*32 + 8*g];
    if (ep == 1){
      acc0 = MFMA_BF16(bf0, af, acc0);
      acc1 = MFMA_BF16(bf1, af, acc1);
    } else {
      acc0 = MFMA_BF16(af, bf0, acc0);
      acc1 = MFMA_BF16(af, bf1, acc1);
    }
  }
  if (ep == 1){
    #pragma unroll
    for (int to=0; to<2; to++){
      f32x4 a = to ? acc1 : acc0;
      #pragma unroll
      for (int r=0;r<4;r++){
        int o = o0 + 16*to + 4*g + r;
        int n = n0 + ln;
        outb[o*8192 + n] = __float2bfloat16(a[r] + bias[o]);
      }
    }
  } else {
    float b0 = bias[o0+ln]*bscale, b1 = bias[o0+16+ln]*bscale;
    #pragma unroll
    for (int to=0; to<2; to++){
      f32x4 a = to ? acc1 : acc0;
      float bb = to ? b1 : b0;
      int o = o0 + 16*to + ln;
      #pragma unroll
      for (int r=0;r<4;r++){
        int n = n0 + 4*g + r;
        float v = a[r] + bb;
        if (ep == 2) v = fmaxf(v, 0.f);
        if (ep == 3) outf[n*128 + o] = 1.f/(1.f + exp2f(-1.44269504f*v));
        else         outb[n*128 + o] = __float2bfloat16(v);
      }
    }
  }
}

// ---------------- fused attention, LDS-staged flash ----------------
// Block: 512 threads = 8 waves. wave w: nt = w&3 (n-tile of 32), mh = w>>2 (m-half).
// Grid: (64, 4). Each step stages K/V 64-m tiles for BOTH halves (16 KB), dbuf.
__global__ __launch_bounds__(512, 2) void attn2(
    const __hip_bfloat16* __restrict__ QT, const __hip_bfloat16* __restrict__ KT,
    const __hip_bfloat16* __restrict__ Vb, __hip_bfloat16* __restrict__ OT)
{
  __shared__ short stage[2][8192];     // [buf][16KB]: K0 V0 K1 V1, 4KB each
  __shared__ float cmb[4][64][16];     // mh=1 partial accs
  __shared__ float cps[4][2][16];      // mh=1 partial psums

  const int tid = threadIdx.x;
  const int w = tid>>6, lane = tid&63, g = lane>>4, ln = lane&15;
  const int nt = w&3, mh = w>>2;
  const int h = blockIdx.y;
  const int nbase = blockIdx.x*128 + nt*32;

  const __hip_bfloat16* Kh = KT + h*32;
  const __hip_bfloat16* Vh = Vb + (size_t)(h*32)*8192;

  // Q fragments (Q pre-scaled by SCALE*log2e)
  s16x8 qf[2];
  qf[0] = *(const s16x8*)&QT[(size_t)(nbase+ln)*128 + h*32 + 8*g];
  qf[1] = *(const s16x8*)&QT[(size_t)(nbase+16+ln)*128 + h*32 + 8*g];

  // ---- staging sources: this thread covers segments 2w and 2w+1 (of 16) ----
  // seg 0-3: K(mh0) rows seg*16.. ; 4-7: V(mh0) c-rows (seg-4)*8.. ; 8-15: same mh1
  const __hip_bfloat16* gp[2];
  int gstep[2], ldoff[2];
  #pragma unroll
  for (int u=0; u<2; u++){
    int seg = 2*w + u;
    int smh = seg>>3, rem = seg&7, isV = rem>>2, sr = rem&3;
    if (!isV){
      int row = sr*16 + (lane>>2);
      int gk  = (lane&3) ^ ((lane>>3)&3);             // source-side K swizzle
      gp[u] = &Kh[(size_t)(smh*4096 + row)*128 + 8*gk];
      gstep[u] = 64*128;
    } else {
      int c  = sr*8 + (lane>>3);
      int p  = lane&7;
      int mc = p ^ (c&7);                              // source-side V swizzle
      gp[u] = &Vh[(size_t)c*8192 + smh*4096 + 8*mc];
      gstep[u] = 64;
    }
    ldoff[u] = seg*512;                                // shorts (1 KB per seg)
  }

  // ---- precomputed LDS read offsets (shorts) ----
  const int kloff = ln*32 + ((g ^ ((ln>>1)&3))<<3);    // + r*512
  const int sig   = (ln&7)<<1;
  int vo[2][2];                                        // [kk][hi], + (16t+ln)*64
  #pragma unroll
  for (int kk=0;kk<2;kk++)
    #pragma unroll
    for (int hi=0;hi<2;hi++)
      vo[kk][hi] = (((8*kk + 4*hi + g) ^ sig)<<2);

  f32x4 acc[2][2];                                     // [t(c-tile)][j(n-half)]
  #pragma unroll
  for (int t=0;t<2;t++){ acc[t][0]=(f32x4){0,0,0,0}; acc[t][1]=(f32x4){0,0,0,0}; }
  float psum[2] = {0.f, 0.f};

  // prologue: stage step 0 into buf 0
  gll16(gp[0], &stage[0][ldoff[0]]);
  gll16(gp[1], &stage[0][ldoff[1]]);
  gp[0] += gstep[0]; gp[1] += gstep[1];
  __syncthreads();

  int buf = 0;
  for (int t=0; t<64; ++t){
    if (t < 63){
      gll16(gp[0], &stage[buf^1][ldoff[0]]);
      gll16(gp[1], &stage[buf^1][ldoff[1]]);
      gp[0] += gstep[0]; gp[1] += gstep[1];
    }
    const short* Kl = &stage[buf][mh*4096];
    const short* Vl = Kl + 2048;

    // K fragments + S^T MFMAs: s[r][j], lane holds S^T[m=64t'+16r+4g+reg][n_j]
    s16x8 kf[4];
    #pragma unroll
    for (int r=0;r<4;r++)
      kf[r] = *(const s16x8*)&Kl[r*512 + kloff];
    f32x4 s[4][2];
    #pragma unroll
    for (int r=0;r<4;r++){
      f32x4 z = {0.f,0.f,0.f,0.f};
      s[r][0] = MFMA_BF16(kf[r], qf[0], z);
      s[r][1] = MFMA_BF16(kf[r], qf[1], z);
    }

    // softmax numerator, fixed max=0 (|logit| small by construction)
    s16x8 pb[2][2];                                    // [kk][j]
    #pragma unroll
    for (int j=0;j<2;j++){
      #pragma unroll
      for (int kk=0; kk<2; kk++){
        #pragma unroll
        for (int i=0;i<4;i++){
          float p0 = exp2f(s[2*kk][j][i]);
          float p1 = exp2f(s[2*kk+1][j][i]);
          psum[j] += p0 + p1;
          pb[kk][j][i]   = bf16s(p0);                  // m = 32kk + 4g + i
          pb[kk][j][i+4] = bf16s(p1);                  // m = 32kk + 16 + 4g + i
        }
      }
    }

    // PV: vf shared across j; same k-bijection as pb
    #pragma unroll
    for (int kk=0; kk<2; kk++){
      #pragma unroll
      for (int ct=0; ct<2; ct++){
        const short* vrow = Vl + (16*ct+ln)*64;
        s16x4 lo = *(const s16x4*)&vrow[vo[kk][0]];
        s16x4 hi = *(const s16x4*)&vrow[vo[kk][1]];
        s16x8 vf = __builtin_shufflevector(lo, hi, 0,1,2,3,4,5,6,7);
        acc[ct][0] = MFMA_BF16(vf, pb[kk][0], acc[ct][0]);
        acc[ct][1] = MFMA_BF16(vf, pb[kk][1], acc[ct][1]);
      }
    }

    __syncthreads();
    buf ^= 1;
  }

  // ---- combine m-halves ----
  #pragma unroll
  for (int j=0;j<2;j++){
    psum[j] += __shfl_xor(psum[j], 16, 64);
    psum[j] += __shfl_xor(psum[j], 32, 64);
  }
  if (mh == 1){
    #pragma unroll
    for (int ct=0; ct<2; ct++)
      #pragma unroll
      for (int j=0;j<2;j++)
        *(f32x4*)&cmb[nt][lane][(ct*2+j)*4] = acc[ct][j];
    if (lane < 32) cps[nt][lane>>4][ln] = psum[lane>>4];
  }
  __syncthreads();
  if (mh == 0){
    float inv[2];
    inv[0] = 1.f/(psum[0] + cps[nt][0][ln]);
    inv[1] = 1.f/(psum[1] + cps[nt][1][ln]);
    #pragma unroll
    for (int ct=0; ct<2; ct++){
      #pragma unroll
      for (int j=0;j<2;j++){
        f32x4 o = acc[ct][j] + *(const f32x4*)&cmb[nt][lane][(ct*2+j)*4];
        s16x4 ob;
        #pragma unroll
        for (int r=0;r<4;r++) ob[r] = bf16s(o[r]*inv[j]);
        *(s16x4*)&OT[(size_t)(nbase+16*j+ln)*128 + h*32 + 16*ct + 4*g] = ob;
      }
    }
  }
}

// ---------------- final gated combine ----------------
__global__ __launch_bounds__(256) void combine(
    const float* __restrict__ feat1, const float* __restrict__ gate,
    const __hip_bfloat16* __restrict__ aot, float* __restrict__ out)
{
  int idx = (blockIdx.x*256 + threadIdx.x)*4;
  int c = idx>>13, nn = idx&8191;
  f32x4 f = *(const f32x4*)&feat1[idx];
  f32x4 r;
  #pragma unroll
  for (int i=0;i<4;i++){
    float gt = gate[(nn+i)*128 + c];
    float ao = __bfloat162float(aot[(nn+i)*128 + c]);
    r[i] = gt*f[i] + (1.f-gt)*ao;
  }
  *(f32x4*)&out[idx] = r;
}

extern "C" void kernel_launch(void* const* d_in, const int* in_sizes, int n_in,
                              void* d_out, int out_size, void* d_ws, size_t ws_size,
                              hipStream_t stream)
{
  const float* feat1 = (const float*)d_in[0];
  const float* feat2 = (const float*)d_in[1];
  const float* Wq = (const float*)d_in[2];  const float* bq = (const float*)d_in[3];
  const float* Wk = (const float*)d_in[4];  const float* bk = (const float*)d_in[5];
  const float* Wv = (const float*)d_in[6];  const float* bv = (const float*)d_in[7];
  const float* Wo = (const float*)d_in[8];  const float* bo = (const float*)d_in[9];
  const float* Wg1 = (const float*)d_in[10]; const float* bg1 = (const float*)d_in[11];
  const float* Wg2 = (const float*)d_in[12]; const float* bg2 = (const float*)d_in[13];

  __hip_bfloat16* WQb  = (__hip_bfloat16*)d_ws;
  __hip_bfloat16* WKb  = WQb + 16384;
  __hip_bfloat16* WVb  = WQb + 32768;
  __hip_bfloat16* WOb  = WQb + 49152;
  __hip_bfloat16* WG1b = WQb + 65536;
  __hip_bfloat16* WG2b = WQb + 98304;
  __hip_bfloat16* F1T  = WQb + 114688;
  __hip_bfloat16* F2T  = F1T + 1048576;
  __hip_bfloat16* QT   = F1T + 2*1048576;
  __hip_bfloat16* KT   = F1T + 3*1048576;
  __hip_bfloat16* Vbf  = F1T + 4*1048576;
  __hip_bfloat16* OT   = F1T + 5*1048576;
  __hip_bfloat16* AOT  = F1T + 6*1048576;
  __hip_bfloat16* G1T  = F1T + 7*1048576;
  float*          GATE = (float*)(F1T + 8*1048576);

  const float SCQ = 0.17677669529663689f * 1.44269504088896340f;

  wprep<<<448,256,0,stream>>>(Wq,Wk,Wv,Wo,Wg1,Wg2,WQb);
  transpose_to_bf16<<<128,256,0,stream>>>(feat1, F1T);
  transpose_to_bf16<<<128,256,0,stream>>>(feat2, F2T);
  gemmT<4,4><<<512,256,0,stream>>>(F1T,F1T,WQb,128,bq,SCQ, QT ,nullptr,0);
  gemmT<4,4><<<512,256,0,stream>>>(F2T,F2T,WKb,128,bk,1.f, KT ,nullptr,0);
  gemmT<4,4><<<512,256,0,stream>>>(F2T,F2T,WVb,128,bv,1.f, Vbf,nullptr,1);
  attn2<<<dim3(64,4),512,0,stream>>>(QT,KT,Vbf,OT);
  gemmT<4,4><<<512,256,0,stream>>>(OT ,OT ,WOb ,128,bo ,1.f, AOT,nullptr,0);
  gemmT<8,4><<<512,256,0,stream>>>(AOT,F1T,WG1b,256,bg1,1.f, G1T,nullptr,2);
  gemmT<4,4><<<512,256,0,stream>>>(G1T,G1T,WG2b,128,bg2,1.f, nullptr,GATE,3);
  combine<<<1024,256,0,stream>>>(feat1, GATE, AOT, (float*)d_out);
}

// Round 3
// 153.574 us; speedup vs baseline: 2.5826x; 1.0218x over previous
//
#include <hip/hip_runtime.h>
#include <hip/hip_bf16.h>

// I2I CrossAttention + gate fusion, MI355X (gfx950).
// B=1, C=128, D*H*W = N = 8192, HEADS=4, DH=32.
// Round 3: attn -> counted-vmcnt 3-buffer pipeline (T3+T4), 512 blocks x 4 waves,
//          raw s_barrier + s_waitcnt vmcnt(4) (prefetch stays in flight across
//          barriers), s_setprio around MFMA clusters (T5); combine fused into
//          the gate-GEMM epilogue.

typedef __attribute__((ext_vector_type(4))) float f32x4;
typedef __attribute__((ext_vector_type(8))) short s16x8;
typedef __attribute__((ext_vector_type(4))) short s16x4;

#define MFMA_BF16(A,B,C) __builtin_amdgcn_mfma_f32_16x16x32_bf16((A),(B),(C),0,0,0)

static __device__ inline short bf16s(float f){
  __hip_bfloat16 h = __float2bfloat16(f);
  return __builtin_bit_cast(short, h);
}

__device__ __forceinline__ void gll16(const void* g, void* l){
  __builtin_amdgcn_global_load_lds(
      (const __attribute__((address_space(1))) void*)g,
      (__attribute__((address_space(3))) void*)l, 16, 0, 0);
}

// ---------------- weight prep: fp32 -> bf16 (Wq scaled) ----------------
__global__ __launch_bounds__(256) void wprep(
    const float* __restrict__ Wq, const float* __restrict__ Wk,
    const float* __restrict__ Wv, const float* __restrict__ Wo,
    const float* __restrict__ Wg1, const float* __restrict__ Wg2,
    __hip_bfloat16* __restrict__ out)
{
  int i = blockIdx.x*256 + threadIdx.x;              // 0..114687
  const float SCQ = 0.17677669529663689f * 1.44269504088896340f;
  float v;
  if      (i < 16384) v = Wq[i]*SCQ;
  else if (i < 32768) v = Wk[i-16384];
  else if (i < 49152) v = Wv[i-32768];
  else if (i < 65536) v = Wo[i-49152];
  else if (i < 98304) v = Wg1[i-65536];
  else                v = Wg2[i-98304];
  out[i] = __float2bfloat16(v);
}

// ------------- transpose [128][8192] fp32 -> [8192][128] bf16 -------------
__global__ __launch_bounds__(256) void transpose_to_bf16(
    const float* __restrict__ in, __hip_bfloat16* __restrict__ out)
{
  __shared__ __hip_bfloat16 tile[64][128];
  int tid = threadIdx.x;
  int n0 = blockIdx.x*64;
  int cq = tid>>4;
  int nq = (tid&15)*4;
  #pragma unroll
  for (int r=0;r<8;r++){
    int c = r*16 + cq;
    f32x4 val = *(const f32x4*)&in[c*8192 + n0 + nq];
    #pragma unroll
    for (int i=0;i<4;i++){
      int n = nq + i;
      tile[n][c ^ ((n&7)<<4)] = __float2bfloat16(val[i]);
    }
  }
  __syncthreads();
  int row = tid>>2;
  int cb  = (tid&3)*32;
  #pragma unroll
  for (int k=0;k<4;k++){
    int c0 = cb + 8*k;
    s16x8 v = *(const s16x8*)&tile[row][c0 ^ ((row&7)<<4)];
    *(s16x8*)&out[(n0+row)*128 + c0] = v;
  }
}

// ---------------- generic transposed-output channel-mix GEMM ----------------
// ep: 0 = bf16 [n][128]; 1 = V variant bf16 [o][8192]; 2 = relu bf16 [n][128];
//     3 = sigmoid gate FUSED with final combine: out[c][n] = g*f1 + (1-g)*ao
template<int KCH, int SPLIT>
__global__ __launch_bounds__(256) void gemmT(
    const __hip_bfloat16* __restrict__ A1, const __hip_bfloat16* __restrict__ A2,
    const __hip_bfloat16* __restrict__ Bw, const int bstride,
    const float* __restrict__ bias, const float bscale,
    __hip_bfloat16* __restrict__ outb, const int ep,
    const float* __restrict__ xf1, const __hip_bfloat16* __restrict__ xao,
    float* __restrict__ xout)
{
  int tid = threadIdx.x;
  int w = tid>>6, lane = tid&63, g = lane>>4, ln = lane&15;
  int n0 = blockIdx.x*16, o0 = w*32;
  f32x4 acc0 = {0.f,0.f,0.f,0.f}, acc1 = {0.f,0.f,0.f,0.f};
  #pragma unroll
  for (int ck=0; ck<KCH; ck++){
    const __hip_bfloat16* As = (ck < SPLIT) ? A1 : A2;
    int cb = ((ck < SPLIT) ? ck : (ck-SPLIT))*32;
    s16x8 af  = *(const s16x8*)&As[(n0+ln)*128 + cb + 8*g];
    s16x8 bf0 = *(const s16x8*)&Bw[(o0+ln)*bstride + ck*32 + 8*g];
    s16x8 bf1 = *(const s16x8*)&Bw[(o0+16+ln)*bstride + ck*32 + 8*g];
    if (ep == 1){
      acc0 = MFMA_BF16(bf0, af, acc0);
      acc1 = MFMA_BF16(bf1, af, acc1);
    } else {
      acc0 = MFMA_BF16(af, bf0, acc0);
      acc1 = MFMA_BF16(af, bf1, acc1);
    }
  }
  if (ep == 1){
    #pragma unroll
    for (int to=0; to<2; to++){
      f32x4 a = to ? acc1 : acc0;
      #pragma unroll
      for (int r=0;r<4;r++){
        int o = o0 + 16*to + 4*g + r;
        int n = n0 + ln;
        outb[o*8192 + n] = __float2bfloat16(a[r] + bias[o]);
      }
    }
  } else {
    float b0 = bias[o0+ln]*bscale, b1 = bias[o0+16+ln]*bscale;
    #pragma unroll
    for (int to=0; to<2; to++){
      f32x4 a = to ? acc1 : acc0;
      float bb = to ? b1 : b0;
      int o = o0 + 16*to + ln;
      #pragma unroll
      for (int r=0;r<4;r++){
        int n = n0 + 4*g + r;
        float v = a[r] + bb;
        if (ep == 2) v = fmaxf(v, 0.f);
        if (ep == 3){
          float gt = 1.f/(1.f + exp2f(-1.44269504f*v));
          float f1 = xf1[(size_t)o*8192 + n];
          float ao = __bfloat162float(xao[n*128 + o]);
          xout[(size_t)o*8192 + n] = gt*f1 + (1.f - gt)*ao;
        } else {
          outb[n*128 + o] = __float2bfloat16(v);
        }
      }
    }
  }
}

// ---------------- fused attention, counted-vmcnt pipelined flash ----------------
// Block: 256 threads = 4 waves. wave w: nt = w&1 (n-tile of 32), mh = w>>1.
// Grid: (128, 4) = 512 blocks (2/CU). 3 LDS buffers, loads 2 steps in flight.
__global__ __launch_bounds__(256, 2) void attn3(
    const __hip_bfloat16* __restrict__ QT, const __hip_bfloat16* __restrict__ KT,
    const __hip_bfloat16* __restrict__ Vb, __hip_bfloat16* __restrict__ OT)
{
  __shared__ short stage[3][8192];     // [buf][16KB]: K0 V0 K1 V1 (4KB each)
  __shared__ float cmb[2][64][16];     // mh=1 partial accs
  __shared__ float cps[2][2][16];      // mh=1 partial psums

  const int tid = threadIdx.x;
  const int w = tid>>6, lane = tid&63, g = lane>>4, ln = lane&15;
  const int nt = w&1, mh = w>>1;
  const int h = blockIdx.y;
  const int nbase = blockIdx.x*64 + nt*32;

  const __hip_bfloat16* Kh = KT + h*32;
  const __hip_bfloat16* Vh = Vb + (size_t)(h*32)*8192;

  // Q fragments (Q pre-scaled by SCALE*log2e)
  s16x8 qf[2];
  qf[0] = *(const s16x8*)&QT[(size_t)(nbase+ln)*128 + h*32 + 8*g];
  qf[1] = *(const s16x8*)&QT[(size_t)(nbase+16+ln)*128 + h*32 + 8*g];

  // ---- staging sources: this thread covers segments 4w..4w+3 (of 16 x 1KB) ----
  // seg 0-3: K(mh0) rows seg*16.. ; 4-7: V(mh0) c-rows (seg-4)*8.. ; 8-15: mh1
  const __hip_bfloat16* gp[4];
  int gstep[4], ldoff[4];
  #pragma unroll
  for (int u=0; u<4; u++){
    int seg = 4*w + u;
    int smh = seg>>3, rem = seg&7, isV = rem>>2, sr = rem&3;
    if (!isV){
      int row = sr*16 + (lane>>2);
      int gk  = (lane&3) ^ ((lane>>3)&3);             // source-side K swizzle
      gp[u] = &Kh[(size_t)(smh*4096 + row)*128 + 8*gk];
      gstep[u] = 64*128;
    } else {
      int c  = sr*8 + (lane>>3);
      int p  = lane&7;
      int mc = p ^ (c&7);                              // source-side V swizzle
      gp[u] = &Vh[(size_t)c*8192 + smh*4096 + 8*mc];
      gstep[u] = 64;
    }
    ldoff[u] = seg*512;                                // shorts (1 KB per seg)
  }
  short* sb = &stage[0][0];

  #define ISSUE(OFF) { \
    _Pragma("unroll") \
    for (int u=0;u<4;u++){ gll16(gp[u], sb + (OFF) + ldoff[u]); gp[u] += gstep[u]; } }

  // ---- precomputed LDS read offsets (shorts) ----
  const int kloff = mh*4096 + ln*32 + ((g ^ ((ln>>1)&3))<<3);   // + r*512
  const int sig   = (ln&7)<<1;
  int vo[2][2];
  #pragma unroll
  for (int kk=0;kk<2;kk++)
    #pragma unroll
    for (int hi=0;hi<2;hi++)
      vo[kk][hi] = (((8*kk + 4*hi + g) ^ sig)<<2);

  f32x4 acc[2][2];                                     // [ct][j]
  #pragma unroll
  for (int t=0;t<2;t++){ acc[t][0]=(f32x4){0,0,0,0}; acc[t][1]=(f32x4){0,0,0,0}; }
  float psum[2] = {0.f, 0.f};

  // prologue: stage steps 0,1 into bufs 0,1 (8 loads in flight per thread)
  ISSUE(0);
  ISSUE(8192);

  unsigned roff = 0, ioff = 16384;
  for (int t=0; t<64; ++t){
    // S(t) complete (S(t+1)'s 4 loads may remain in flight across the barrier)
    asm volatile("s_waitcnt vmcnt(4)" ::: "memory");
    __builtin_amdgcn_s_barrier();
    // issue S(t+2) into the buffer last read at t-1 (block-wide done per barrier).
    // Tail issues (t>=62) read valid workspace and land in never-read buffers.
    ISSUE(ioff);
    ioff = (ioff == 16384u) ? 0u : ioff + 8192u;

    const short* Kl = sb + roff;
    const short* Vl = Kl + mh*4096 + 2048;
    roff = (roff == 16384u) ? 0u : roff + 8192u;

    // K fragments + S^T MFMAs: lane holds S^T[m=64t+16r+4g+reg][n_j]
    s16x8 kf[4];
    #pragma unroll
    for (int r=0;r<4;r++)
      kf[r] = *(const s16x8*)&Kl[r*512 + kloff];
    f32x4 s[4][2];
    __builtin_amdgcn_s_setprio(1);
    #pragma unroll
    for (int r=0;r<4;r++){
      f32x4 z = {0.f,0.f,0.f,0.f};
      s[r][0] = MFMA_BF16(kf[r], qf[0], z);
      s[r][1] = MFMA_BF16(kf[r], qf[1], z);
    }
    __builtin_amdgcn_s_setprio(0);

    // V fragments early (LDS latency hides under softmax VALU)
    s16x8 vf[2][2];                                    // [kk][ct]
    #pragma unroll
    for (int kk=0; kk<2; kk++){
      #pragma unroll
      for (int ct=0; ct<2; ct++){
        const short* vrow = Vl + (16*ct+ln)*64;
        s16x4 lo = *(const s16x4*)&vrow[vo[kk][0]];
        s16x4 hi = *(const s16x4*)&vrow[vo[kk][1]];
        vf[kk][ct] = __builtin_shufflevector(lo, hi, 0,1,2,3,4,5,6,7);
      }
    }

    // softmax numerator, fixed max=0 (|logit| small by construction)
    s16x8 pb[2][2];                                    // [kk][j]
    #pragma unroll
    for (int j=0;j<2;j++){
      float ps0 = 0.f, ps1 = 0.f;
      #pragma unroll
      for (int kk=0; kk<2; kk++){
        #pragma unroll
        for (int i=0;i<4;i++){
          float p0 = exp2f(s[2*kk][j][i]);
          float p1 = exp2f(s[2*kk+1][j][i]);
          ps0 += p0; ps1 += p1;
          pb[kk][j][i]   = bf16s(p0);                  // m = 32kk + 4g + i
          pb[kk][j][i+4] = bf16s(p1);                  // m = 32kk + 16 + 4g + i
        }
      }
      psum[j] += ps0 + ps1;
    }

    // PV: same k-bijection on both operands
    __builtin_amdgcn_s_setprio(1);
    #pragma unroll
    for (int kk=0; kk<2; kk++){
      #pragma unroll
      for (int ct=0; ct<2; ct++){
        acc[ct][0] = MFMA_BF16(vf[kk][ct], pb[kk][0], acc[ct][0]);
        acc[ct][1] = MFMA_BF16(vf[kk][ct], pb[kk][1], acc[ct][1]);
      }
    }
    __builtin_amdgcn_s_setprio(0);
  }
  #undef ISSUE

  // ---- combine m-halves ----
  #pragma unroll
  for (int j=0;j<2;j++){
    psum[j] += __shfl_xor(psum[j], 16, 64);
    psum[j] += __shfl_xor(psum[j], 32, 64);
  }
  if (mh == 1){
    #pragma unroll
    for (int ct=0; ct<2; ct++)
      #pragma unroll
      for (int j=0;j<2;j++)
        *(f32x4*)&cmb[nt][lane][(ct*2+j)*4] = acc[ct][j];
    if (lane < 32) cps[nt][lane>>4][ln] = psum[lane>>4];
  }
  __syncthreads();
  if (mh == 0){
    float inv[2];
    inv[0] = 1.f/(psum[0] + cps[nt][0][ln]);
    inv[1] = 1.f/(psum[1] + cps[nt][1][ln]);
    #pragma unroll
    for (int ct=0; ct<2; ct++){
      #pragma unroll
      for (int j=0;j<2;j++){
        f32x4 o = acc[ct][j] + *(const f32x4*)&cmb[nt][lane][(ct*2+j)*4];
        s16x4 ob;
        #pragma unroll
        for (int r=0;r<4;r++) ob[r] = bf16s(o[r]*inv[j]);
        *(s16x4*)&OT[(size_t)(nbase+16*j+ln)*128 + h*32 + 16*ct + 4*g] = ob;
      }
    }
  }
}

extern "C" void kernel_launch(void* const* d_in, const int* in_sizes, int n_in,
                              void* d_out, int out_size, void* d_ws, size_t ws_size,
                              hipStream_t stream)
{
  const float* feat1 = (const float*)d_in[0];
  const float* feat2 = (const float*)d_in[1];
  const float* Wq = (const float*)d_in[2];  const float* bq = (const float*)d_in[3];
  const float* Wk = (const float*)d_in[4];  const float* bk = (const float*)d_in[5];
  const float* Wv = (const float*)d_in[6];  const float* bv = (const float*)d_in[7];
  const float* Wo = (const float*)d_in[8];  const float* bo = (const float*)d_in[9];
  const float* Wg1 = (const float*)d_in[10]; const float* bg1 = (const float*)d_in[11];
  const float* Wg2 = (const float*)d_in[12]; const float* bg2 = (const float*)d_in[13];

  __hip_bfloat16* WQb  = (__hip_bfloat16*)d_ws;
  __hip_bfloat16* WKb  = WQb + 16384;
  __hip_bfloat16* WVb  = WQb + 32768;
  __hip_bfloat16* WOb  = WQb + 49152;
  __hip_bfloat16* WG1b = WQb + 65536;
  __hip_bfloat16* WG2b = WQb + 98304;
  __hip_bfloat16* F1T  = WQb + 114688;
  __hip_bfloat16* F2T  = F1T + 1048576;
  __hip_bfloat16* QT   = F1T + 2*1048576;
  __hip_bfloat16* KT   = F1T + 3*1048576;
  __hip_bfloat16* Vbf  = F1T + 4*1048576;
  __hip_bfloat16* OT   = F1T + 5*1048576;
  __hip_bfloat16* AOT  = F1T + 6*1048576;
  __hip_bfloat16* G1T  = F1T + 7*1048576;

  const float SCQ = 0.17677669529663689f * 1.44269504088896340f;

  wprep<<<448,256,0,stream>>>(Wq,Wk,Wv,Wo,Wg1,Wg2,WQb);
  transpose_to_bf16<<<128,256,0,stream>>>(feat1, F1T);
  transpose_to_bf16<<<128,256,0,stream>>>(feat2, F2T);
  gemmT<4,4><<<512,256,0,stream>>>(F1T,F1T,WQb,128,bq,SCQ, QT ,0,nullptr,nullptr,nullptr);
  gemmT<4,4><<<512,256,0,stream>>>(F2T,F2T,WKb,128,bk,1.f, KT ,0,nullptr,nullptr,nullptr);
  gemmT<4,4><<<512,256,0,stream>>>(F2T,F2T,WVb,128,bv,1.f, Vbf,1,nullptr,nullptr,nullptr);
  attn3<<<dim3(128,4),256,0,stream>>>(QT,KT,Vbf,OT);
  gemmT<4,4><<<512,256,0,stream>>>(OT ,OT ,WOb ,128,bo ,1.f, AOT,0,nullptr,nullptr,nullptr);
  gemmT<8,4><<<512,256,0,stream>>>(AOT,F1T,WG1b,256,bg1,1.f, G1T,2,nullptr,nullptr,nullptr);
  gemmT<4,4><<<512,256,0,stream>>>(G1T,G1T,WG2b,128,bg2,1.f, nullptr,3,feat1,AOT,(float*)d_out);
}

// Round 4
// 112.907 us; speedup vs baseline: 3.5128x; 1.3602x over previous
//
#include <hip/hip_runtime.h>
#include <hip/hip_bf16.h>

// I2I CrossAttention + gate fusion, MI355X (gfx950).
// B=1, C=128, D*H*W = N = 8192, HEADS=4, DH=32.
// Round 4: attn VALU diet — raw v_exp_f32, v_cvt_pk_bf16_f32 packing,
//          psum via ones-MFMA (no VALU adds, no shfl reduce), V fragments as
//          single ds_read_b128 via global-side sigma-permute + bank XOR,
//          2-buffer depth-1 prefetch. Gate sigmoid via v_exp/v_rcp.

typedef __attribute__((ext_vector_type(4))) float f32x4;
typedef __attribute__((ext_vector_type(4))) unsigned u32x4;
typedef __attribute__((ext_vector_type(8))) short s16x8;
typedef __attribute__((ext_vector_type(4))) short s16x4;

#define MFMA_BF16(A,B,C) __builtin_amdgcn_mfma_f32_16x16x32_bf16((A),(B),(C),0,0,0)

static __device__ __forceinline__ float fexp2(float x){
  float r; asm("v_exp_f32 %0, %1" : "=v"(r) : "v"(x)); return r;
}
static __device__ __forceinline__ float frcp(float x){
  float r; asm("v_rcp_f32 %0, %1" : "=v"(r) : "v"(x)); return r;
}
static __device__ __forceinline__ unsigned cvtpk(float lo, float hi){
  unsigned r; asm("v_cvt_pk_bf16_f32 %0, %1, %2" : "=v"(r) : "v"(lo), "v"(hi)); return r;
}
static __device__ inline short bf16s(float f){
  __hip_bfloat16 h = __float2bfloat16(f);
  return __builtin_bit_cast(short, h);
}

__device__ __forceinline__ void gll16(const void* g, void* l){
  __builtin_amdgcn_global_load_lds(
      (const __attribute__((address_space(1))) void*)g,
      (__attribute__((address_space(3))) void*)l, 16, 0, 0);
}

// ---------------- weight prep: fp32 -> bf16 (Wq scaled) ----------------
__global__ __launch_bounds__(256) void wprep(
    const float* __restrict__ Wq, const float* __restrict__ Wk,
    const float* __restrict__ Wv, const float* __restrict__ Wo,
    const float* __restrict__ Wg1, const float* __restrict__ Wg2,
    __hip_bfloat16* __restrict__ out)
{
  int i = blockIdx.x*256 + threadIdx.x;              // 0..114687
  const float SCQ = 0.17677669529663689f * 1.44269504088896340f;
  float v;
  if      (i < 16384) v = Wq[i]*SCQ;
  else if (i < 32768) v = Wk[i-16384];
  else if (i < 49152) v = Wv[i-32768];
  else if (i < 65536) v = Wo[i-49152];
  else if (i < 98304) v = Wg1[i-65536];
  else                v = Wg2[i-98304];
  out[i] = __float2bfloat16(v);
}

// ------------- transpose [128][8192] fp32 -> [8192][128] bf16 -------------
__global__ __launch_bounds__(256) void transpose_to_bf16(
    const float* __restrict__ in, __hip_bfloat16* __restrict__ out)
{
  __shared__ __hip_bfloat16 tile[64][128];
  int tid = threadIdx.x;
  int n0 = blockIdx.x*64;
  int cq = tid>>4;
  int nq = (tid&15)*4;
  #pragma unroll
  for (int r=0;r<8;r++){
    int c = r*16 + cq;
    f32x4 val = *(const f32x4*)&in[c*8192 + n0 + nq];
    #pragma unroll
    for (int i=0;i<4;i++){
      int n = nq + i;
      tile[n][c ^ ((n&7)<<4)] = __float2bfloat16(val[i]);
    }
  }
  __syncthreads();
  int row = tid>>2;
  int cb  = (tid&3)*32;
  #pragma unroll
  for (int k=0;k<4;k++){
    int c0 = cb + 8*k;
    s16x8 v = *(const s16x8*)&tile[row][c0 ^ ((row&7)<<4)];
    *(s16x8*)&out[(n0+row)*128 + c0] = v;
  }
}

// ---------------- generic transposed-output channel-mix GEMM ----------------
// ep: 0 = bf16 [n][128]; 1 = V permuted bf16 [o][8192] (sigma+bankXOR applied);
//     2 = relu bf16 [n][128]; 3 = sigmoid gate fused combine -> fp32 out
template<int KCH, int SPLIT>
__global__ __launch_bounds__(256) void gemmT(
    const __hip_bfloat16* __restrict__ A1, const __hip_bfloat16* __restrict__ A2,
    const __hip_bfloat16* __restrict__ Bw, const int bstride,
    const float* __restrict__ bias, const float bscale,
    __hip_bfloat16* __restrict__ outb, const int ep,
    const float* __restrict__ xf1, const __hip_bfloat16* __restrict__ xao,
    float* __restrict__ xout)
{
  int tid = threadIdx.x;
  int w = tid>>6, lane = tid&63, g = lane>>4, ln = lane&15;
  int n0 = blockIdx.x*16, o0 = w*32;
  f32x4 acc0 = {0.f,0.f,0.f,0.f}, acc1 = {0.f,0.f,0.f,0.f};
  #pragma unroll
  for (int ck=0; ck<KCH; ck++){
    const __hip_bfloat16* As = (ck < SPLIT) ? A1 : A2;
    int cb = ((ck < SPLIT) ? ck : (ck-SPLIT))*32;
    s16x8 af  = *(const s16x8*)&As[(n0+ln)*128 + cb + 8*g];
    s16x8 bf0 = *(const s16x8*)&Bw[(o0+ln)*bstride + ck*32 + 8*g];
    s16x8 bf1 = *(const s16x8*)&Bw[(o0+16+ln)*bstride + ck*32 + 8*g];
    if (ep == 1){
      acc0 = MFMA_BF16(bf0, af, acc0);
      acc1 = MFMA_BF16(bf1, af, acc1);
    } else {
      acc0 = MFMA_BF16(af, bf0, acc0);
      acc1 = MFMA_BF16(af, bf1, acc1);
    }
  }
  if (ep == 1){
    // write V with per-64-block column permute p(m)=32kk+8g'+4h+i, granule
    // XORed by (c&7) so attn's LDS (linear-staged) reads are single b128s.
    #pragma unroll
    for (int to=0; to<2; to++){
      f32x4 a = to ? acc1 : acc0;
      #pragma unroll
      for (int r=0;r<4;r++){
        int o = o0 + 16*to + 4*g + r;
        int n = n0 + ln;
        int m63 = n & 63, blk = n >> 6;
        int Gx = (((m63>>5)<<2) | ((m63>>2)&3)) ^ (o & 7);
        int col = blk*64 + Gx*8 + ((m63>>4)&1)*4 + (m63&3);
        outb[(size_t)o*8192 + col] = __float2bfloat16(a[r] + bias[o]);
      }
    }
  } else {
    float b0 = bias[o0+ln]*bscale, b1 = bias[o0+16+ln]*bscale;
    #pragma unroll
    for (int to=0; to<2; to++){
      f32x4 a = to ? acc1 : acc0;
      float bb = to ? b1 : b0;
      int o = o0 + 16*to + ln;
      #pragma unroll
      for (int r=0;r<4;r++){
        int n = n0 + 4*g + r;
        float v = a[r] + bb;
        if (ep == 2) v = fmaxf(v, 0.f);
        if (ep == 3){
          float gt = frcp(1.f + fexp2(-1.44269504f*v));
          float f1 = xf1[(size_t)o*8192 + n];
          float ao = __bfloat162float(xao[n*128 + o]);
          xout[(size_t)o*8192 + n] = gt*f1 + (1.f - gt)*ao;
        } else {
          outb[n*128 + o] = __float2bfloat16(v);
        }
      }
    }
  }
}

// ---------------- fused attention, VALU-lean pipelined flash ----------------
// Block: 256 threads = 4 waves. wave w: nt = w&1 (n-tile of 32), mh = w>>1.
// Grid: (128, 4) = 512 blocks (2/CU). 2 LDS buffers, depth-1 prefetch.
__global__ __launch_bounds__(256, 2) void attn4(
    const __hip_bfloat16* __restrict__ QT, const __hip_bfloat16* __restrict__ KT,
    const __hip_bfloat16* __restrict__ Vp, __hip_bfloat16* __restrict__ OT)
{
  __shared__ short stage[2][8192];     // [buf][16KB]: K0 V0 K1 V1 (4KB each)
  __shared__ float cmb[2][64][16];     // mh=1 partial accs
  __shared__ float cps[2][2][16];      // mh=1 partial psums

  const int tid = threadIdx.x;
  const int w = tid>>6, lane = tid&63, g = lane>>4, ln = lane&15;
  const int nt = w&1, mh = w>>1;
  const int h = blockIdx.y;
  const int nbase = blockIdx.x*64 + nt*32;

  const __hip_bfloat16* Kh = KT + h*32;
  const __hip_bfloat16* Vh = Vp + (size_t)(h*32)*8192;

  // Q fragments (Q pre-scaled by SCALE*log2e)
  s16x8 qf[2];
  qf[0] = *(const s16x8*)&QT[(size_t)(nbase+ln)*128 + h*32 + 8*g];
  qf[1] = *(const s16x8*)&QT[(size_t)(nbase+16+ln)*128 + h*32 + 8*g];

  // ---- staging sources: thread covers segments 4w..4w+3 (16 x 1KB) ----
  // seg 0-3: K(mh0) rows seg*16.. ; 4-7: V(mh0, linear: Vp pre-permuted);
  // 8-15: same for mh1. gll dest = uniform base (+ lane*16B by HW).
  const __hip_bfloat16* gp[4];
  int gstep[4], ldoff[4];
  #pragma unroll
  for (int u=0; u<4; u++){
    int seg = 4*w + u;
    int smh = seg>>3, rem = seg&7, isV = rem>>2, sr = rem&3;
    if (!isV){
      int row = sr*16 + (lane>>2);
      int gk  = (lane&3) ^ ((lane>>3)&3);             // source-side K swizzle
      gp[u] = &Kh[(size_t)(smh*4096 + row)*128 + 8*gk];
      gstep[u] = 64*128;
    } else {
      int c = sr*8 + (lane>>3);                        // linear V copy
      gp[u] = &Vh[(size_t)c*8192 + smh*4096 + 8*(lane&7)];
      gstep[u] = 64;
    }
    ldoff[u] = seg*512;                                // shorts (1 KB per seg)
  }
  short* sb = &stage[0][0];

  #define ISSUE(OFF) { \
    _Pragma("unroll") \
    for (int u=0;u<4;u++){ gll16(gp[u], sb + (OFF) + ldoff[u]); gp[u] += gstep[u]; } }

  // ---- LDS read offsets (shorts) ----
  const int kloff = ln*32 + ((g ^ ((ln>>1)&3))<<3);    // + r*512, within K half
  int voff[2];                                         // [kk], + (16ct+ln)*64
  voff[0] = 8*((g  ) ^ (ln&7));
  voff[1] = 8*((g+4) ^ (ln&7));

  const u32x4 onesw = {0x3F803F80u,0x3F803F80u,0x3F803F80u,0x3F803F80u};
  const s16x8 onesf = __builtin_bit_cast(s16x8, onesw);

  f32x4 acc[2][2];                                     // [ct][j]
  #pragma unroll
  for (int t=0;t<2;t++){ acc[t][0]=(f32x4){0,0,0,0}; acc[t][1]=(f32x4){0,0,0,0}; }
  f32x4 accS[2] = {(f32x4){0,0,0,0},(f32x4){0,0,0,0}};  // ones-MFMA psum

  ISSUE(0);                                            // prologue: step 0
  for (int t=0; t<64; ++t){
    asm volatile("s_waitcnt vmcnt(0)" ::: "memory");   // my 4 loads done
    __builtin_amdgcn_s_barrier();                      // => all waves' loads done
    const int cur = (t&1)<<13, nxt = 8192 - cur;
    ISSUE(nxt);                                        // prefetch t+1 (depth-1)

    const short* Kl = sb + cur + mh*4096;
    const short* Vl = Kl + 2048;

    // K fragments + S^T MFMAs: lane holds S^T[m=16r+4g+reg][n_j]
    s16x8 kf[4];
    #pragma unroll
    for (int r=0;r<4;r++)
      kf[r] = *(const s16x8*)&Kl[r*512 + kloff];
    f32x4 s[4][2];
    __builtin_amdgcn_s_setprio(1);
    #pragma unroll
    for (int r=0;r<4;r++){
      f32x4 z = {0.f,0.f,0.f,0.f};
      s[r][0] = MFMA_BF16(kf[r], qf[0], z);
      s[r][1] = MFMA_BF16(kf[r], qf[1], z);
    }
    __builtin_amdgcn_s_setprio(0);

    // V fragments: single b128 each (global side pre-permuted + bank-XORed)
    s16x8 vf[2][2];                                    // [kk][ct]
    #pragma unroll
    for (int kk=0; kk<2; kk++)
      #pragma unroll
      for (int ct=0; ct<2; ct++)
        vf[kk][ct] = *(const s16x8*)&Vl[(16*ct+ln)*64 + voff[kk]];

    // softmax numerator, fixed max=0; raw v_exp + v_cvt_pk_bf16_f32
    s16x8 pb[2][2];                                    // [kk][j]
    #pragma unroll
    for (int j=0;j<2;j++){
      #pragma unroll
      for (int kk=0; kk<2; kk++){
        float p0 = fexp2(s[2*kk  ][j][0]), p1 = fexp2(s[2*kk  ][j][1]);
        float p2 = fexp2(s[2*kk  ][j][2]), p3 = fexp2(s[2*kk  ][j][3]);
        float q0 = fexp2(s[2*kk+1][j][0]), q1 = fexp2(s[2*kk+1][j][1]);
        float q2 = fexp2(s[2*kk+1][j][2]), q3 = fexp2(s[2*kk+1][j][3]);
        u32x4 pw;
        pw[0] = cvtpk(p0,p1); pw[1] = cvtpk(p2,p3);
        pw[2] = cvtpk(q0,q1); pw[3] = cvtpk(q2,q3);
        pb[kk][j] = __builtin_bit_cast(s16x8, pw);
      }
    }

    // PV + psum (ones-MFMA): all on the matrix pipe
    __builtin_amdgcn_s_setprio(1);
    #pragma unroll
    for (int kk=0; kk<2; kk++){
      #pragma unroll
      for (int ct=0; ct<2; ct++){
        acc[ct][0] = MFMA_BF16(vf[kk][ct], pb[kk][0], acc[ct][0]);
        acc[ct][1] = MFMA_BF16(vf[kk][ct], pb[kk][1], acc[ct][1]);
      }
      accS[0] = MFMA_BF16(onesf, pb[kk][0], accS[0]);
      accS[1] = MFMA_BF16(onesf, pb[kk][1], accS[1]);
    }
    __builtin_amdgcn_s_setprio(0);
  }
  #undef ISSUE

  // ---- combine m-halves; accS[j][0] == psum for n = nbase+16j+ln (all lanes)
  if (mh == 1){
    #pragma unroll
    for (int ct=0; ct<2; ct++)
      #pragma unroll
      for (int j=0;j<2;j++)
        *(f32x4*)&cmb[nt][lane][(ct*2+j)*4] = acc[ct][j];
    if (lane < 16){ cps[nt][0][lane] = accS[0][0]; cps[nt][1][lane] = accS[1][0]; }
  }
  __syncthreads();
  if (mh == 0){
    float inv[2];
    inv[0] = frcp(accS[0][0] + cps[nt][0][ln]);
    inv[1] = frcp(accS[1][0] + cps[nt][1][ln]);
    #pragma unroll
    for (int ct=0; ct<2; ct++){
      #pragma unroll
      for (int j=0;j<2;j++){
        f32x4 o = acc[ct][j] + *(const f32x4*)&cmb[nt][lane][(ct*2+j)*4];
        unsigned lo = cvtpk(o[0]*inv[j], o[1]*inv[j]);
        unsigned hi = cvtpk(o[2]*inv[j], o[3]*inv[j]);
        u32x4 dummy; (void)dummy;
        unsigned long long pk = ((unsigned long long)hi<<32) | lo;
        *(unsigned long long*)&OT[(size_t)(nbase+16*j+ln)*128 + h*32 + 16*ct + 4*g] = pk;
      }
    }
  }
}

extern "C" void kernel_launch(void* const* d_in, const int* in_sizes, int n_in,
                              void* d_out, int out_size, void* d_ws, size_t ws_size,
                              hipStream_t stream)
{
  const float* feat1 = (const float*)d_in[0];
  const float* feat2 = (const float*)d_in[1];
  const float* Wq = (const float*)d_in[2];  const float* bq = (const float*)d_in[3];
  const float* Wk = (const float*)d_in[4];  const float* bk = (const float*)d_in[5];
  const float* Wv = (const float*)d_in[6];  const float* bv = (const float*)d_in[7];
  const float* Wo = (const float*)d_in[8];  const float* bo = (const float*)d_in[9];
  const float* Wg1 = (const float*)d_in[10]; const float* bg1 = (const float*)d_in[11];
  const float* Wg2 = (const float*)d_in[12]; const float* bg2 = (const float*)d_in[13];

  __hip_bfloat16* WQb  = (__hip_bfloat16*)d_ws;
  __hip_bfloat16* WKb  = WQb + 16384;
  __hip_bfloat16* WVb  = WQb + 32768;
  __hip_bfloat16* WOb  = WQb + 49152;
  __hip_bfloat16* WG1b = WQb + 65536;
  __hip_bfloat16* WG2b = WQb + 98304;
  __hip_bfloat16* F1T  = WQb + 114688;
  __hip_bfloat16* F2T  = F1T + 1048576;
  __hip_bfloat16* QT   = F1T + 2*1048576;
  __hip_bfloat16* KT   = F1T + 3*1048576;
  __hip_bfloat16* Vbf  = F1T + 4*1048576;
  __hip_bfloat16* OT   = F1T + 5*1048576;
  __hip_bfloat16* AOT  = F1T + 6*1048576;
  __hip_bfloat16* G1T  = F1T + 7*1048576;

  const float SCQ = 0.17677669529663689f * 1.44269504088896340f;

  wprep<<<448,256,0,stream>>>(Wq,Wk,Wv,Wo,Wg1,Wg2,WQb);
  transpose_to_bf16<<<128,256,0,stream>>>(feat1, F1T);
  transpose_to_bf16<<<128,256,0,stream>>>(feat2, F2T);
  gemmT<4,4><<<512,256,0,stream>>>(F1T,F1T,WQb,128,bq,SCQ, QT ,0,nullptr,nullptr,nullptr);
  gemmT<4,4><<<512,256,0,stream>>>(F2T,F2T,WKb,128,bk,1.f, KT ,0,nullptr,nullptr,nullptr);
  gemmT<4,4><<<512,256,0,stream>>>(F2T,F2T,WVb,128,bv,1.f, Vbf,1,nullptr,nullptr,nullptr);
  attn4<<<dim3(128,4),256,0,stream>>>(QT,KT,Vbf,OT);
  gemmT<4,4><<<512,256,0,stream>>>(OT ,OT ,WOb ,128,bo ,1.f, AOT,0,nullptr,nullptr,nullptr);
  gemmT<8,4><<<512,256,0,stream>>>(AOT,F1T,WG1b,256,bg1,1.f, G1T,2,nullptr,nullptr,nullptr);
  gemmT<4,4><<<512,256,0,stream>>>(G1T,G1T,WG2b,128,bg2,1.f, nullptr,3,feat1,AOT,(float*)d_out);
}